// Round 17
// baseline (1507.173 us; speedup 1.0000x reference)
//
#include <hip/hip_runtime.h>
#include <hip/hip_bf16.h>

#define N_NODES 25000
#define N_EDGES 400000
#define H 128
#define NB 8           // nodes per block in node_update
#define NBM 16         // nodes per block in node_mlp

__global__ void init_s_kernel(const int* __restrict__ species,
                              const float* __restrict__ emb,
                              float* __restrict__ s) {
    int idx = blockIdx.x * blockDim.x + threadIdx.x;
    if (idx < N_NODES * H) {
        int n = idx >> 7;
        int h = idx & 127;
        s[idx] = emb[species[n] * H + h];
    }
}

// ---------- CSR build over senders ----------
__global__ void count_kernel(const int* __restrict__ senders, int* __restrict__ cnt) {
    int e = blockIdx.x * blockDim.x + threadIdx.x;
    if (e < N_EDGES) atomicAdd(&cnt[senders[e]], 1);
}

__global__ __launch_bounds__(1024) void scan_kernel(int* __restrict__ cnt,
                                                    int* __restrict__ offsets) {
    __shared__ int sh[1024];
    const int t = threadIdx.x;
    const int CH = 25;                    // 1024*25 >= 25000
    int base = t * CH;
    int lc[CH];
    int lsum = 0;
    #pragma unroll
    for (int i = 0; i < CH; i++) {
        int idx = base + i;
        int c = (idx < N_NODES) ? cnt[idx] : 0;
        lc[i] = c; lsum += c;
    }
    sh[t] = lsum;
    __syncthreads();
    for (int ofs = 1; ofs < 1024; ofs <<= 1) {
        int v = (t >= ofs) ? sh[t - ofs] : 0;
        __syncthreads();
        sh[t] += v;
        __syncthreads();
    }
    int run = (t > 0) ? sh[t - 1] : 0;
    #pragma unroll
    for (int i = 0; i < CH; i++) {
        int idx = base + i;
        if (idx < N_NODES) {
            offsets[idx] = run;
            cnt[idx] = run;               // cnt becomes the fill cursor
            run += lc[i];
        }
    }
    if (t == 1023) offsets[N_NODES] = sh[1023];
}

__global__ void fill_kernel(const int* __restrict__ senders,
                            int* __restrict__ cursor, int* __restrict__ edge_ids) {
    int e = blockIdx.x * blockDim.x + threadIdx.x;
    if (e < N_EDGES) {
        int pos = atomicAdd(&cursor[senders[e]], 1);
        edge_ids[pos] = e;
    }
}

// rbf[e][n] = sqrt(2)*sin((n+1)*pi*d)/d
__global__ void rbfenv_kernel(const float* __restrict__ dists,
                              float* __restrict__ rbf) {
    int idx = blockIdx.x * blockDim.x + threadIdx.x;
    if (idx < N_EDGES * 20) {
        int e = idx / 20;
        int n = idx - e * 20;
        float d = dists[e];
        const float PI = 3.14159265358979323846f;
        rbf[idx] = 1.4142135623730951f * sinf((float)(n + 1) * PI * d) / d;
    }
}

// Transpose all weight matrices (both layers) into [col][row] layouts so
// thread-per-column kernels can do float4 weight loads along h.
// Segments (per layer): W1 128x128, W2 128x384, Wvm 128x256, Wm1 256x128, Wm2 128x384
#define SZ_W1  (128 * 128)
#define SZ_W2  (128 * 384)
#define SZ_WVM (128 * 256)
#define SZ_WM1 (256 * 128)
#define SZ_WM2 (128 * 384)
#define T_TOTAL (2 * (SZ_W1 + SZ_W2 + SZ_WVM + SZ_WM1 + SZ_WM2))

__global__ void transpose_all_kernel(
    const float* __restrict__ W1, const float* __restrict__ W2,
    const float* __restrict__ Wvm, const float* __restrict__ Wm1,
    const float* __restrict__ Wm2,
    float* __restrict__ W1T, float* __restrict__ W2T,
    float* __restrict__ WvmT, float* __restrict__ Wm1T,
    float* __restrict__ Wm2T)
{
    int idx = blockIdx.x * blockDim.x + threadIdx.x;
    const float* src; float* dst; int R, C, per;
    if (idx < 2 * SZ_W1) { src = W1; dst = W1T; R = 128; C = 128; per = SZ_W1; }
    else if ((idx -= 2 * SZ_W1) < 2 * SZ_W2)  { src = W2;  dst = W2T;  R = 128; C = 384; per = SZ_W2; }
    else if ((idx -= 2 * SZ_W2) < 2 * SZ_WVM) { src = Wvm; dst = WvmT; R = 128; C = 256; per = SZ_WVM; }
    else if ((idx -= 2 * SZ_WVM) < 2 * SZ_WM1){ src = Wm1; dst = Wm1T; R = 256; C = 128; per = SZ_WM1; }
    else if ((idx -= 2 * SZ_WM1) < 2 * SZ_WM2){ src = Wm2; dst = Wm2T; R = 128; C = 384; per = SZ_WM2; }
    else return;
    int layer = idx / per;
    int rem = idx - layer * per;
    int r = rem / C;
    int c = rem - r * C;
    dst[layer * per + c * R + r] = src[layer * per + rem];
}

// x = silu(s @ W1[i] + b1[i]) @ W2[i] + b2[i]   (per node: 128 -> 128 -> 384)
// Weights consumed from transposed layouts: float4 loads along h.
__global__ __launch_bounds__(128, 4) void node_mlp_kernel(
    const float* __restrict__ s,
    const float* __restrict__ W1T, const float* __restrict__ b1,
    const float* __restrict__ W2T, const float* __restrict__ b2,
    float* __restrict__ x, int layer)
{
    __shared__ float s_sh[NBM][H];
    __shared__ float hid_sh[NBM][H];
    const int t = threadIdx.x;
    const int n0 = blockIdx.x * NBM;

    #pragma unroll
    for (int nb = 0; nb < NBM; nb++) {
        int n = n0 + nb;
        s_sh[nb][t] = (n < N_NODES) ? s[(size_t)n * H + t] : 0.f;
    }
    __syncthreads();

    const float* W1p = W1T + (size_t)layer * SZ_W1 + (size_t)t * H;  // row t, h-contig
    float b1v = b1[layer * H + t];
    float acc[NBM];
    #pragma unroll
    for (int nb = 0; nb < NBM; nb++) acc[nb] = b1v;
    for (int h = 0; h < H; h += 4) {
        float4 w = *(const float4*)&W1p[h];
        #pragma unroll
        for (int nb = 0; nb < NBM; nb++) {
            float4 sv = *(const float4*)&s_sh[nb][h];
            acc[nb] = fmaf(sv.x, w.x, fmaf(sv.y, w.y,
                      fmaf(sv.z, w.z, fmaf(sv.w, w.w, acc[nb]))));
        }
    }
    #pragma unroll
    for (int nb = 0; nb < NBM; nb++) {
        float z = acc[nb];
        hid_sh[nb][t] = z / (1.f + expf(-z));   // silu
    }
    __syncthreads();

    const float* W2p0 = W2T + (size_t)layer * SZ_W2 + (size_t)t * H;
    const float* W2p1 = W2p0 + (size_t)128 * H;
    const float* W2p2 = W2p0 + (size_t)256 * H;
    float c0 = b2[layer * 384 + t];
    float c1 = b2[layer * 384 + 128 + t];
    float c2 = b2[layer * 384 + 256 + t];
    float a0[NBM], a1[NBM], a2[NBM];
    #pragma unroll
    for (int nb = 0; nb < NBM; nb++) { a0[nb] = c0; a1[nb] = c1; a2[nb] = c2; }
    for (int h = 0; h < H; h += 4) {
        float4 w0 = *(const float4*)&W2p0[h];
        float4 w1 = *(const float4*)&W2p1[h];
        float4 w2 = *(const float4*)&W2p2[h];
        #pragma unroll
        for (int nb = 0; nb < NBM; nb++) {
            float4 hv = *(const float4*)&hid_sh[nb][h];
            a0[nb] = fmaf(hv.x, w0.x, fmaf(hv.y, w0.y,
                     fmaf(hv.z, w0.z, fmaf(hv.w, w0.w, a0[nb]))));
            a1[nb] = fmaf(hv.x, w1.x, fmaf(hv.y, w1.y,
                     fmaf(hv.z, w1.z, fmaf(hv.w, w1.w, a1[nb]))));
            a2[nb] = fmaf(hv.x, w2.x, fmaf(hv.y, w2.y,
                     fmaf(hv.z, w2.z, fmaf(hv.w, w2.w, a2[nb]))));
        }
    }
    #pragma unroll
    for (int nb = 0; nb < NBM; nb++) {
        int n = n0 + nb;
        if (n < N_NODES) {
            x[(size_t)n * 384 + t]       = a0[nb];
            x[(size_t)n * 384 + 128 + t] = a1[nb];
            x[(size_t)n * 384 + 256 + t] = a2[nb];
        }
    }
}

// Gather-based edge aggregation: one block (128 threads) per sender node.
// #pragma unroll 2 on the edge loop: interleave two edges' gather loads.
__global__ __launch_bounds__(128, 4) void aggregate_kernel(
    const int* __restrict__ receivers,
    const int* __restrict__ offsets, const int* __restrict__ edge_ids,
    const float* __restrict__ dir_ij, const float* __restrict__ dists,
    const float* __restrict__ rbf,
    const float* __restrict__ Wf, const float* __restrict__ bfb,
    const float* __restrict__ x, const float* __restrict__ v,
    float* __restrict__ ds_acc, float* __restrict__ dv_acc, int layer)
{
    const int t = threadIdx.x;          // feature 0..127
    const int node = blockIdx.x;

    const float* Wfp = Wf + layer * 384;       // row stride 768 (L*3*H)
    float wf0[20], wf1[20], wf2[20];
    #pragma unroll
    for (int n = 0; n < 20; n++) {
        wf0[n] = Wfp[n * 768 + t];
        wf1[n] = Wfp[n * 768 + 128 + t];
        wf2[n] = Wfp[n * 768 + 256 + t];
    }
    float bf0 = bfb[layer * 384 + t];
    float bf1 = bfb[layer * 384 + 128 + t];
    float bf2 = bfb[layer * 384 + 256 + t];

    float accs = 0.f, av0 = 0.f, av1 = 0.f, av2 = 0.f;
    const int beg = offsets[node], end = offsets[node + 1];

    #pragma unroll 2
    for (int j = beg; j < end; j++) {
        int eid = edge_ids[j];
        int rcv = receivers[eid];
        float d  = dists[eid];
        float d0 = dir_ij[eid * 3 + 0];
        float d1 = dir_ij[eid * 3 + 1];
        float d2 = dir_ij[eid * 3 + 2];

        float u = d;
        float u2 = u * u, u4 = u2 * u2, u6 = u4 * u2, u7 = u6 * u, u8 = u4 * u4;
        float env = (u < 1.f) ? (1.f - 28.f * u6 + 48.f * u7 - 21.f * u8) : 0.f;

        const float4* rp = (const float4*)(rbf + (size_t)eid * 20);
        float4 q0 = rp[0], q1 = rp[1], q2 = rp[2], q3 = rp[3], q4 = rp[4];
        float r[20] = { q0.x, q0.y, q0.z, q0.w, q1.x, q1.y, q1.z, q1.w,
                        q2.x, q2.y, q2.z, q2.w, q3.x, q3.y, q3.z, q3.w,
                        q4.x, q4.y, q4.z, q4.w };

        float w0 = bf0, w1 = bf1, w2 = bf2;
        #pragma unroll
        for (int n = 0; n < 20; n++) {
            w0 = fmaf(r[n], wf0[n], w0);
            w1 = fmaf(r[n], wf1[n], w1);
            w2 = fmaf(r[n], wf2[n], w2);
        }
        const float* xr = x + (size_t)rcv * 384;
        const float* vr = v + (size_t)rcv * 384;
        float phi0 = w0 * env * xr[t];
        float phi1 = w1 * env * xr[128 + t];
        float phi2 = w2 * env * xr[256 + t];

        accs += phi0;
        av0 = fmaf(phi1, d0, fmaf(phi2, vr[t],       av0));
        av1 = fmaf(phi1, d1, fmaf(phi2, vr[128 + t], av1));
        av2 = fmaf(phi1, d2, fmaf(phi2, vr[256 + t], av2));
    }

    ds_acc[(size_t)node * H + t] = accs;
    dv_acc[(size_t)node * 384 + t]       = av0;
    dv_acc[(size_t)node * 384 + 128 + t] = av1;
    dv_acc[(size_t)node * 384 + 256 + t] = av2;
}

// Apply segment sums, then gated vector/scalar mixing block.
// Transposed weights -> float4 weight loads. LDS 20KB; hid aliases ts_sh.
__global__ __launch_bounds__(128, 4) void node_update_kernel(
    float* __restrict__ s, float* __restrict__ v,
    const float* __restrict__ ds_acc, const float* __restrict__ dv_acc,
    const float* __restrict__ WvmT,
    const float* __restrict__ Wm1T, const float* __restrict__ bm1,
    const float* __restrict__ Wm2T, const float* __restrict__ bm2,
    const float* __restrict__ eps_raw_p, int layer)
{
    __shared__ float v_sh[NB][3][H];
    __shared__ float ts_sh[NB][2 * H];   // reused as hid after Wm1 loop
    const int t = threadIdx.x;
    const int n0 = blockIdx.x * NB;
    float er = eps_raw_p[0];
    float eps = rsqrtf(1.f + er * er);

    float s_new[NB];
    #pragma unroll
    for (int nb = 0; nb < NB; nb++) {
        int n = n0 + nb;
        if (n < N_NODES) {
            float sv = (s[(size_t)n * H + t] + ds_acc[(size_t)n * H + t]) * eps;
            s_new[nb] = sv;
            #pragma unroll
            for (int k = 0; k < 3; k++) {
                float vv = (v[(size_t)n * 384 + k * H + t] +
                            dv_acc[(size_t)n * 384 + k * H + t]) * eps;
                v_sh[nb][k][t] = vv;
            }
        } else {
            s_new[nb] = 0.f;
            #pragma unroll
            for (int k = 0; k < 3; k++) v_sh[nb][k][t] = 0.f;
        }
    }
    __syncthreads();

    // vw = v @ Wvm[i]; thread t holds columns t (v_l) and 128+t (v_r)
    const float* Wvl = WvmT + (size_t)layer * SZ_WVM + (size_t)t * H;         // col t
    const float* Wvr = WvmT + (size_t)layer * SZ_WVM + (size_t)(128 + t) * H; // col 128+t
    float vl[NB][3], vr[NB][3];
    #pragma unroll
    for (int nb = 0; nb < NB; nb++)
        #pragma unroll
        for (int k = 0; k < 3; k++) { vl[nb][k] = 0.f; vr[nb][k] = 0.f; }
    for (int h = 0; h < H; h += 4) {
        float4 wl = *(const float4*)&Wvl[h];
        float4 wr = *(const float4*)&Wvr[h];
        #pragma unroll
        for (int nb = 0; nb < NB; nb++) {
            #pragma unroll
            for (int k = 0; k < 3; k++) {
                float4 vv = *(const float4*)&v_sh[nb][k][h];
                vl[nb][k] = fmaf(vv.x, wl.x, fmaf(vv.y, wl.y,
                            fmaf(vv.z, wl.z, fmaf(vv.w, wl.w, vl[nb][k]))));
                vr[nb][k] = fmaf(vv.x, wr.x, fmaf(vv.y, wr.y,
                            fmaf(vv.z, wr.z, fmaf(vv.w, wr.w, vr[nb][k]))));
            }
        }
    }

    #pragma unroll
    for (int nb = 0; nb < NB; nb++) {
        float vn = sqrtf(vr[nb][0] * vr[nb][0] + vr[nb][1] * vr[nb][1] +
                         vr[nb][2] * vr[nb][2] + 1e-8f);
        ts_sh[nb][t] = s_new[nb];
        ts_sh[nb][128 + t] = vn;
    }
    __syncthreads();

    const float* Wm1p = Wm1T + (size_t)layer * SZ_WM1 + (size_t)t * 256; // col t, h-contig (256)
    float hb = bm1[layer * H + t];
    float hacc[NB];
    #pragma unroll
    for (int nb = 0; nb < NB; nb++) hacc[nb] = hb;
    for (int h = 0; h < 2 * H; h += 4) {
        float4 w = *(const float4*)&Wm1p[h];
        #pragma unroll
        for (int nb = 0; nb < NB; nb++) {
            float4 tv = *(const float4*)&ts_sh[nb][h];
            hacc[nb] = fmaf(tv.x, w.x, fmaf(tv.y, w.y,
                       fmaf(tv.z, w.z, fmaf(tv.w, w.w, hacc[nb]))));
        }
    }
    __syncthreads();   // all ts reads done before aliasing

    #pragma unroll
    for (int nb = 0; nb < NB; nb++) {
        float z = hacc[nb];
        ts_sh[nb][t] = z / (1.f + expf(-z));   // hid aliases ts
    }
    __syncthreads();

    const float* Wm2p0 = Wm2T + (size_t)layer * SZ_WM2 + (size_t)t * H;
    const float* Wm2p1 = Wm2p0 + (size_t)128 * H;
    const float* Wm2p2 = Wm2p0 + (size_t)256 * H;
    float c0 = bm2[layer * 384 + t];
    float c1 = bm2[layer * 384 + 128 + t];
    float c2 = bm2[layer * 384 + 256 + t];
    float m0[NB], m1[NB], m2[NB];
    #pragma unroll
    for (int nb = 0; nb < NB; nb++) { m0[nb] = c0; m1[nb] = c1; m2[nb] = c2; }
    for (int h = 0; h < H; h += 4) {
        float4 w0 = *(const float4*)&Wm2p0[h];
        float4 w1 = *(const float4*)&Wm2p1[h];
        float4 w2 = *(const float4*)&Wm2p2[h];
        #pragma unroll
        for (int nb = 0; nb < NB; nb++) {
            float4 hv = *(const float4*)&ts_sh[nb][h];
            m0[nb] = fmaf(hv.x, w0.x, fmaf(hv.y, w0.y,
                     fmaf(hv.z, w0.z, fmaf(hv.w, w0.w, m0[nb]))));
            m1[nb] = fmaf(hv.x, w1.x, fmaf(hv.y, w1.y,
                     fmaf(hv.z, w1.z, fmaf(hv.w, w1.w, m1[nb]))));
            m2[nb] = fmaf(hv.x, w2.x, fmaf(hv.y, w2.y,
                     fmaf(hv.z, w2.z, fmaf(hv.w, w2.w, m2[nb]))));
        }
    }

    #pragma unroll
    for (int nb = 0; nb < NB; nb++) {
        int n = n0 + nb;
        if (n >= N_NODES) continue;
        float sum_lr = vr[nb][0] * vl[nb][0] + vr[nb][1] * vl[nb][1] +
                       vr[nb][2] * vl[nb][2];
        float s_out = (s_new[nb] + m0[nb] + m2[nb] * sum_lr) * eps;
        s[(size_t)n * H + t] = s_out;
        #pragma unroll
        for (int k = 0; k < 3; k++) {
            v[(size_t)n * 384 + k * H + t] =
                (v_sh[nb][k][t] + vl[nb][k] * m1[nb]) * eps;
        }
    }
}

extern "C" void kernel_launch(void* const* d_in, const int* in_sizes, int n_in,
                              void* d_out, int out_size, void* d_ws, size_t ws_size,
                              hipStream_t stream) {
    const int*   species   = (const int*)d_in[0];
    const int*   senders   = (const int*)d_in[1];
    const int*   receivers = (const int*)d_in[2];
    const float* dir_ij    = (const float*)d_in[3];
    const float* dists     = (const float*)d_in[4];
    const float* emb       = (const float*)d_in[5];
    const float* Wf        = (const float*)d_in[6];
    const float* bf        = (const float*)d_in[7];
    const float* W1        = (const float*)d_in[8];
    const float* b1        = (const float*)d_in[9];
    const float* W2        = (const float*)d_in[10];
    const float* b2        = (const float*)d_in[11];
    const float* Wvm       = (const float*)d_in[12];
    const float* Wm1       = (const float*)d_in[13];
    const float* bm1       = (const float*)d_in[14];
    const float* Wm2       = (const float*)d_in[15];
    const float* bm2       = (const float*)d_in[16];
    const float* eps_raw   = (const float*)d_in[17];

    float* s = (float*)d_out;                            // N*H
    float* v = (float*)d_out + (size_t)N_NODES * H;      // N*3*H

    float* x      = (float*)d_ws;                        // N*384
    float* ds_acc = x + (size_t)N_NODES * 384;           // N*128
    float* dv_acc = ds_acc + (size_t)N_NODES * H;        // N*384
    int*   cursor   = (int*)(dv_acc + (size_t)N_NODES * 384);  // N
    int*   offsets  = cursor + N_NODES;                        // N+1 (+pad)
    int*   edge_ids = offsets + N_NODES + 8;                   // E
    float* rbf      = (float*)(edge_ids + N_EDGES);            // E*20
    float* W1T  = rbf + (size_t)N_EDGES * 20;                  // transposed weights
    float* W2T  = W1T + 2 * SZ_W1;
    float* WvmT = W2T + 2 * SZ_W2;
    float* Wm1T = WvmT + 2 * SZ_WVM;
    float* Wm2T = Wm1T + 2 * SZ_WM1;

    // CSR build (layer-independent) + rbf + weight transposes
    hipMemsetAsync(cursor, 0, N_NODES * sizeof(int), stream);
    count_kernel<<<(N_EDGES + 255) / 256, 256, 0, stream>>>(senders, cursor);
    scan_kernel<<<1, 1024, 0, stream>>>(cursor, offsets);
    fill_kernel<<<(N_EDGES + 255) / 256, 256, 0, stream>>>(senders, cursor, edge_ids);
    rbfenv_kernel<<<(N_EDGES * 20 + 255) / 256, 256, 0, stream>>>(dists, rbf);
    transpose_all_kernel<<<(T_TOTAL + 255) / 256, 256, 0, stream>>>(
        W1, W2, Wvm, Wm1, Wm2, W1T, W2T, WvmT, Wm1T, Wm2T);

    // init: v = 0, s = emb[species]
    hipMemsetAsync(v, 0, (size_t)N_NODES * 384 * sizeof(float), stream);
    init_s_kernel<<<(N_NODES * H + 255) / 256, 256, 0, stream>>>(species, emb, s);

    for (int layer = 0; layer < 2; layer++) {
        node_mlp_kernel<<<(N_NODES + NBM - 1) / NBM, 128, 0, stream>>>(
            s, W1T, b1, W2T, b2, x, layer);
        aggregate_kernel<<<N_NODES, 128, 0, stream>>>(
            receivers, offsets, edge_ids, dir_ij, dists, rbf, Wf, bf, x, v,
            ds_acc, dv_acc, layer);
        node_update_kernel<<<(N_NODES + NB - 1) / NB, 128, 0, stream>>>(
            s, v, ds_acc, dv_acc, WvmT, Wm1T, bm1, Wm2T, bm2, eps_raw, layer);
    }
}